// Round 14
// baseline (158.995 us; speedup 1.0000x reference)
//
#include <hip/hip_runtime.h>

// TorchPatchNN: unfold(7x7) -> NN argmin over 8100 keys (D=147) -> gather value -> fold mean.
// Round 19: occupancy via thinner waves at CONSTANT block tile. R18: k_nn 63.2us,
//  MfmaUtil 46%, occ 28.9% -- MFMA duty ~49%, rest is latency with <3 waves/SIMD cover.
//  R10's occupancy play failed because it halved the BLOCK (2x per-block fixed costs).
//  This keeps block=128x128, grid=4096, but 8 waves x (64x32 tiles) x 512 threads:
//   - acc 4x2 f32x4 = 32 AGPR; 12 frag loads/wave (48 VGPR) -> ~100 regs total;
//     __launch_bounds__(512,4) -> 2 blocks/CU = 4 waves/SIMD = 50% occ (was 29%).
//   - per-wave L2 traffic 12KB/chunk (was 16KB); per-block totals unchanged; no barriers.
//   - epilogue: 2x shfl_xor (1,2) pre-combine -> redu stays [128][17] u64 (R18 proved
//     conflict-free); final scan 4 threads/row. u64 lexicographic min == tie rule.
//  Numerics identical (same operands, same per-output accumulation order).
//  Keep: merged acc (lo UNSCALED), 16x16x32 shape (R15: 32x32 RAW-serializes), direct-L2
//  frag loads, XCD swizzle, setprio, R18 k_prep/k_fold.
//  Falsifier: occ up + dur flat => TLP lever exhausted; remaining gap is dependency
//  structure + fixed ~78us non-k_nn bucket => near practical floor.

#define NQ 8100
#define NK 8100
#define DD 147
#define HO 90
#define IMG 96
#define NCH 5                 // K chunks of 32 (160 padded K)
#define CST 262144            // f16 per chunk plane: 512 groups x 512
#define ARRN (NCH * CST)      // f16 per array

typedef _Float16 half8 __attribute__((ext_vector_type(8)));
typedef float f32x4 __attribute__((ext_vector_type(4)));

// ---------------- prep: split Q/K into fp16 hi/lo (frag order) + key norms + init ---------
__global__ void k_prep(const float* __restrict__ query, const float* __restrict__ key,
                       _Float16* __restrict__ Qh, _Float16* __restrict__ Ql,
                       _Float16* __restrict__ Kh, _Float16* __restrict__ Kl,
                       float* __restrict__ kn, unsigned long long* __restrict__ fidx64) {
    const int bx = blockIdx.x;
    const bool isK = (blockIdx.y != 0);

    if (bx >= 640) {                      // fused k_kn region: 128 blocks on y==1
        if (!isK) return;
        int wave = threadIdx.x >> 6, lane = threadIdx.x & 63;
        int kb = ((bx - 640) * 4 + wave) * 16;
        for (int r = 0; r < 16; ++r) {
            int k = kb + r;
            float s = 0.f;
            if (k < NK)
                for (int d = lane; d < DD; d += 64) {
                    float v = key[k * DD + d];
                    s += v * v;
                }
#pragma unroll
            for (int off = 32; off; off >>= 1) s += __shfl_down(s, off, 64);
            if (lane == 0) {
                kn[k] = (k < NK) ? s : 1e30f;
                fidx64[k] = 0xFFFFFFFFFFFFFFFFull;   // ws re-poisoned every launch
            }
        }
        return;
    }

    int t = bx * 256 + threadIdx.x;             // 0 .. 163839 (ARRN/8)
    int c = t >> 15;                            // chunk
    int rem = t & 32767;                        // g*64 + lane
    int col = ((rem >> 6) << 4) + (rem & 15);   // g*16 + l15
    int quad = (rem >> 4) & 3;
    int kbase = c * 32 + quad * 8;

    float v[8];
#pragma unroll
    for (int j = 0; j < 8; ++j) {
        int k = kbase + j;
        float x = 0.f;
        if (k < DD && col < NQ) {
            if (isK) {
                x = key[col * DD + k];
            } else {
                int c3 = k / 49, r2 = k - 49 * c3;
                int rr = r2 / 7, ss = r2 - 7 * rr;
                int y = col / HO, xx = col - HO * y;
                x = query[(c3 * IMG + y + rr) * IMG + xx + ss];
            }
        }
        v[j] = x;
    }
    half8 h8, l8;
#pragma unroll
    for (int j = 0; j < 8; ++j) {
        _Float16 h = (_Float16)v[j];
        h8[j] = h;
        l8[j] = (_Float16)(v[j] - (float)h);   // UNSCALED lo (merged-acc scheme)
    }
    if (isK) {
        *(half8*)(Kh + t * 8) = h8;
        *(half8*)(Kl + t * 8) = l8;
    } else {
        *(half8*)(Qh + t * 8) = h8;
        *(half8*)(Ql + t * 8) = l8;
    }
}

// ---------------- main: merged-acc split-f16 MFMA Q.K^T + fused argmin ----------------
// 512 threads = 8 waves of 64x32 tiles on a 128x128 block; barrier-free K-loop;
// acc[4][2] (32 AGPR); 2 blocks/CU target (4 waves/SIMD).
__launch_bounds__(512, 4)
__global__ void k_nn(const _Float16* __restrict__ Qh, const _Float16* __restrict__ Ql,
                     const _Float16* __restrict__ Kh, const _Float16* __restrict__ Kl,
                     const float* __restrict__ kn, unsigned long long* __restrict__ out) {
    __shared__ __align__(16) char smem[17408];   // epilogue reduction: [128][17] u64

    const int tid = (int)threadIdx.x;
    const int wave = tid >> 6, lane = tid & 63;
    const int l15 = lane & 15, quad = lane >> 4;

    // XCD-aware swizzle: blockIdx%8 == XCD. Per XCD: 16qt x 32kt rectangle =>
    // Q 1.28 MB + K 2.56 MB = 3.84 MB <= 4 MiB L2.
    const int b = (int)blockIdx.x;
    const int xcd = b & 7;
    const int i = b >> 3;                         // 0..511 within XCD
    const int qt = (xcd >> 1) * 16 + (i & 15);
    const int kt = (xcd & 1) * 32 + (i >> 4);

    const int mbase = (wave >> 2) * 64;           // wave tile: 64x32 within 128x128
    const int nbase = (wave & 3) * 32;
    const int q0 = qt * 128, n0 = kt * 128;

    // frag-linear global bases (coalesced 16B/lane, L2-hot under the swizzle)
    const int agrp = (mbase >> 4);                // (wave>>2)*4
    const int bgrp = (nbase >> 4);                // (wave&3)*2
    const _Float16* gQh = Qh + (qt * 8 + agrp) * 512 + lane * 8;
    const _Float16* gQl = Ql + (qt * 8 + agrp) * 512 + lane * 8;
    const _Float16* gKh = Kh + (kt * 8 + bgrp) * 512 + lane * 8;
    const _Float16* gKl = Kl + (kt * 8 + bgrp) * 512 + lane * 8;

    f32x4 acc[4][2];                              // 32 AGPR
#pragma unroll
    for (int ii = 0; ii < 4; ++ii)
#pragma unroll
        for (int j = 0; j < 2; ++j)
            acc[ii][j] = (f32x4)0.f;

#pragma unroll
    for (int c = 0; c < NCH; ++c) {
        // 12 independent coalesced loads; no barrier anywhere in the K-loop.
        half8 ah[4], al[4], bh[2], bl[2];
#pragma unroll
        for (int mt = 0; mt < 4; ++mt) {
            ah[mt] = *(const half8*)(gQh + c * CST + mt * 512);
            al[mt] = *(const half8*)(gQl + c * CST + mt * 512);
        }
#pragma unroll
        for (int nt = 0; nt < 2; ++nt) {
            bh[nt] = *(const half8*)(gKh + c * CST + nt * 512);
            bl[nt] = *(const half8*)(gKl + c * CST + nt * 512);
        }

        __builtin_amdgcn_s_setprio(1);
#pragma unroll
        for (int nt = 0; nt < 2; ++nt) {
#pragma unroll
            for (int mt = 0; mt < 4; ++mt) {
                acc[mt][nt] = __builtin_amdgcn_mfma_f32_16x16x32_f16(ah[mt], bh[nt], acc[mt][nt], 0, 0, 0);
                acc[mt][nt] = __builtin_amdgcn_mfma_f32_16x16x32_f16(ah[mt], bl[nt], acc[mt][nt], 0, 0, 0);
                acc[mt][nt] = __builtin_amdgcn_mfma_f32_16x16x32_f16(al[mt], bh[nt], acc[mt][nt], 0, 0, 0);
            }
        }
        __builtin_amdgcn_s_setprio(0);
    }

    // epilogue: dist = kn - 2*acc; packed order-preserving u64; two shfl_xor combines
    // (1 then 2) -> each surviving lane covers 8 cols -> redu [128][17] u64.
    float knv[2];
    int nglob[2];
#pragma unroll
    for (int nt = 0; nt < 2; ++nt) {
        nglob[nt] = n0 + nbase + nt * 16 + l15;
        knv[nt] = kn[nglob[nt]];
    }
    unsigned long long* redu = (unsigned long long*)smem;   // [128][17] u64
    const int cidx = (nbase >> 3) + (l15 >> 2);             // 0..15 after 2 combines

#pragma unroll
    for (int mt = 0; mt < 4; ++mt)
#pragma unroll
        for (int r = 0; r < 4; ++r) {
            float bv = 1e38f;
            int bn = 0x7fffffff;
#pragma unroll
            for (int nt = 0; nt < 2; ++nt) {   // ascending n within lane -> strict < ok
                float d = knv[nt] - 2.0f * acc[mt][nt][r];
                if (d < bv) { bv = d; bn = nglob[nt]; }
            }
            unsigned u = __float_as_uint(bv);
            u = (u & 0x80000000u) ? ~u : (u | 0x80000000u);   // order-preserving map
            unsigned long long pk = ((unsigned long long)u << 32) | (unsigned)bn;
            unsigned long long po = __shfl_xor(pk, 1, 64);    // combine col pairs
            pk = (po < pk) ? po : pk;
            po = __shfl_xor(pk, 2, 64);                       // combine col quads
            pk = (po < pk) ? po : pk;
            if (!(lane & 3)) {
                int m = mbase + mt * 16 + quad * 4 + r;        // C row = quad*4 + reg
                redu[m * 17 + cidx] = pk;
            }
        }
    __syncthreads();

    {   // 4 threads/row, 4 u64-min each, 2-step shfl combine
        int row = tid >> 2;                       // 0..127
        int base = (tid & 3) * 4;
        unsigned long long best = 0xFFFFFFFFFFFFFFFFull;
        const unsigned long long* rp = redu + row * 17 + base;
#pragma unroll
        for (int t2 = 0; t2 < 4; ++t2) {
            unsigned long long v = rp[t2];
            best = (v < best) ? v : best;
        }
        unsigned long long other = __shfl_xor(best, 1, 64);
        best = (other < best) ? other : best;
        other = __shfl_xor(best, 2, 64);
        best = (other < best) ? other : best;
        if (!(tid & 3)) atomicMin(&out[q0 + row], best);
    }
}

// ---------------- gather + fold (overlap-add mean) ----------------
// 8 lanes per output pixel: lane-slot s=0..6 handles patch-row i=s (7 j-loads, ILP 7),
// s=7 idle; shfl_down(width=8) tree reduces; s==0 divides by ANALYTIC count and stores.
// 864 blocks x 256 = 13.5 waves/CU.
__global__ void k_fold(const float* __restrict__ value,
                       const unsigned long long* __restrict__ fidx64,
                       float* __restrict__ out) {
    int t = blockIdx.x * 256 + threadIdx.x;   // 3*96*96*8 = 221184
    int pix = t >> 3, s = t & 7;
    if (pix >= 3 * IMG * IMG) return;
    int c = pix / (IMG * IMG);
    int rem = pix % (IMG * IMG);
    int Y = rem / IMG, X = rem % IMG;

    float partial = 0.f;
    int yy = Y - s;
    if (s < 7 && (unsigned)yy < (unsigned)HO) {
        const unsigned* fidx32 = (const unsigned*)fidx64;   // low word = row index
        const float* vbase = value + c * 49 + s * 7;
        int rows[7];
        bool oks[7];
#pragma unroll
        for (int j = 0; j < 7; ++j) {
            int xx = X - j;
            bool ok = (unsigned)xx < (unsigned)HO;
            int p = ok ? (yy * HO + xx) : 0;
            rows[j] = (int)fidx32[2 * p];
            oks[j] = ok;
        }
#pragma unroll
        for (int j = 0; j < 7; ++j) {
            float v = vbase[rows[j] * DD + j];   // always in-bounds (row 0 when masked)
            if (oks[j]) partial += v;
        }
    }
    partial += __shfl_down(partial, 4, 8);
    partial += __shfl_down(partial, 2, 8);
    partial += __shfl_down(partial, 1, 8);
    if (s == 0) {
        int i0 = max(0, Y - (HO - 1)), i1 = min(6, Y);
        int j0 = max(0, X - (HO - 1)), j1 = min(6, X);
        float cnt = (float)((i1 - i0 + 1) * (j1 - j0 + 1));
        out[pix] = partial / cnt;
    }
}

extern "C" void kernel_launch(void* const* d_in, const int* in_sizes, int n_in,
                              void* d_out, int out_size, void* d_ws, size_t ws_size,
                              hipStream_t stream) {
    const float* query = (const float*)d_in[0];
    const float* key   = (const float*)d_in[1];
    const float* value = (const float*)d_in[2];
    float* out = (float*)d_out;

    _Float16* Qh = (_Float16*)d_ws;           // ARRN f16 each
    _Float16* Ql = Qh + ARRN;
    _Float16* Kh = Ql + ARRN;
    _Float16* Kl = Kh + ARRN;
    float* kn = (float*)(Kl + ARRN);          // 8192 f32
    unsigned long long* fidx64 = (unsigned long long*)(kn + 8192);   // 8192 u64

    dim3 gp(768, 2);   // 640 split blocks + 128 fused-kn blocks (y==1)
    k_prep<<<gp, 256, 0, stream>>>(query, key, Qh, Ql, Kh, Kl, kn, fidx64);
    k_nn<<<4096, 512, 0, stream>>>(Qh, Ql, Kh, Kl, kn, fidx64);
    k_fold<<<864, 256, 0, stream>>>(value, fidx64, out);
}

// Round 15
// 140.314 us; speedup vs baseline: 1.1331x; 1.1331x over previous
//
#include <hip/hip_runtime.h>

// TorchPatchNN: unfold(7x7) -> NN argmin over 8100 keys (D=147) -> gather value -> fold mean.
// Round 20: exact restore of R18 (best measured: total 141.7us, k_nn 63.2us).
//  R19 verdict: thinner waves (8x 64x32) raised occupancy 29->41% but REGRESSED k_nn to
//  88.5us -- A-strips loaded by 4 waves instead of 2 => 1.5x redundant L2 traffic, and
//  per-wave MFMA cover per load halved. Occupancy lever closed from BOTH sides now
//  (R10/R19 thin = worse; R14/R18 fat = optimum).
//  Accumulated A/B evidence at this point:
//   - 16x16x32 > 32x32x16 here (R15: 4 acc chains RAW-serialize).
//   - Barrier-free direct-L2 frag loads ~= LDS staging (R8 vs R12), simpler + fewer regs.
//   - Merged acc (lo UNSCALED) frees 64 AGPR (R13) -> launch_bounds(256,3) occ bump (R14).
//   - [128][17] u64 epilogue: bank conflicts 1M -> 0, LDS 17.4KB (R18).
//   - sched_group_barrier pinning hurts (R7); setprio(1) compute-only helps (~6us, R8).
//   - Cooperative fusion refuted: grid.sync + threadfence cost ~130-150us on non-coherent
//     per-XCD L2 (R17); 3 separate launches are cheaper.
//  Remaining time: k_nn ~63us (MfmaUtil 46%, FETCH at data minimum, 0 conflicts) +
//  ~78us non-k_nn dominated by launch/harness overhead. All counter-guided levers probed.

#define NQ 8100
#define NK 8100
#define DD 147
#define HO 90
#define IMG 96
#define NCH 5                 // K chunks of 32 (160 padded K)
#define CST 262144            // f16 per chunk plane: 512 groups x 512
#define ARRN (NCH * CST)      // f16 per array

typedef _Float16 half8 __attribute__((ext_vector_type(8)));
typedef float f32x4 __attribute__((ext_vector_type(4)));

// ---------------- prep: split Q/K into fp16 hi/lo (frag order) + key norms + init ---------
__global__ void k_prep(const float* __restrict__ query, const float* __restrict__ key,
                       _Float16* __restrict__ Qh, _Float16* __restrict__ Ql,
                       _Float16* __restrict__ Kh, _Float16* __restrict__ Kl,
                       float* __restrict__ kn, unsigned long long* __restrict__ fidx64) {
    const int bx = blockIdx.x;
    const bool isK = (blockIdx.y != 0);

    if (bx >= 640) {                      // fused k_kn region: 128 blocks on y==1
        if (!isK) return;
        int wave = threadIdx.x >> 6, lane = threadIdx.x & 63;
        int kb = ((bx - 640) * 4 + wave) * 16;
        for (int r = 0; r < 16; ++r) {
            int k = kb + r;
            float s = 0.f;
            if (k < NK)
                for (int d = lane; d < DD; d += 64) {
                    float v = key[k * DD + d];
                    s += v * v;
                }
#pragma unroll
            for (int off = 32; off; off >>= 1) s += __shfl_down(s, off, 64);
            if (lane == 0) {
                kn[k] = (k < NK) ? s : 1e30f;
                fidx64[k] = 0xFFFFFFFFFFFFFFFFull;   // ws re-poisoned every launch
            }
        }
        return;
    }

    int t = bx * 256 + threadIdx.x;             // 0 .. 163839 (ARRN/8)
    int c = t >> 15;                            // chunk
    int rem = t & 32767;                        // g*64 + lane
    int col = ((rem >> 6) << 4) + (rem & 15);   // g*16 + l15
    int quad = (rem >> 4) & 3;
    int kbase = c * 32 + quad * 8;

    float v[8];
#pragma unroll
    for (int j = 0; j < 8; ++j) {
        int k = kbase + j;
        float x = 0.f;
        if (k < DD && col < NQ) {
            if (isK) {
                x = key[col * DD + k];
            } else {
                int c3 = k / 49, r2 = k - 49 * c3;
                int rr = r2 / 7, ss = r2 - 7 * rr;
                int y = col / HO, xx = col - HO * y;
                x = query[(c3 * IMG + y + rr) * IMG + xx + ss];
            }
        }
        v[j] = x;
    }
    half8 h8, l8;
#pragma unroll
    for (int j = 0; j < 8; ++j) {
        _Float16 h = (_Float16)v[j];
        h8[j] = h;
        l8[j] = (_Float16)(v[j] - (float)h);   // UNSCALED lo (merged-acc scheme)
    }
    if (isK) {
        *(half8*)(Kh + t * 8) = h8;
        *(half8*)(Kl + t * 8) = l8;
    } else {
        *(half8*)(Qh + t * 8) = h8;
        *(half8*)(Ql + t * 8) = l8;
    }
}

// ---------------- main: merged-acc split-f16 MFMA Q.K^T + fused argmin ----------------
// Barrier-free K-loop, single acc[4][4] (64 AGPR), 17.4KB epilogue LDS, 3 blocks/CU target.
__launch_bounds__(256, 3)
__global__ void k_nn(const _Float16* __restrict__ Qh, const _Float16* __restrict__ Ql,
                     const _Float16* __restrict__ Kh, const _Float16* __restrict__ Kl,
                     const float* __restrict__ kn, unsigned long long* __restrict__ out) {
    __shared__ __align__(16) char smem[17408];   // epilogue reduction: [128][17] u64

    const int tid = (int)threadIdx.x;
    const int wave = tid >> 6, lane = tid & 63;
    const int l15 = lane & 15, quad = lane >> 4;

    // XCD-aware swizzle: blockIdx%8 == XCD. Per XCD: 16qt x 32kt rectangle =>
    // Q 1.28 MB + K 2.56 MB = 3.84 MB <= 4 MiB L2.
    const int b = (int)blockIdx.x;
    const int xcd = b & 7;
    const int i = b >> 3;                         // 0..511 within XCD
    const int qt = (xcd >> 1) * 16 + (i & 15);
    const int kt = (xcd & 1) * 32 + (i >> 4);

    const int mbase = (wave >> 1) * 64;           // wave tile: 64x64 within 128x128
    const int nbase = (wave & 1) * 64;
    const int q0 = qt * 128, n0 = kt * 128;

    // frag-linear global bases (coalesced 16B/lane, L2-hot under the swizzle)
    const int agrp = (mbase >> 4);
    const int bgrp = (nbase >> 4);
    const _Float16* gQh = Qh + (qt * 8 + agrp) * 512 + lane * 8;
    const _Float16* gQl = Ql + (qt * 8 + agrp) * 512 + lane * 8;
    const _Float16* gKh = Kh + (kt * 8 + bgrp) * 512 + lane * 8;
    const _Float16* gKl = Kl + (kt * 8 + bgrp) * 512 + lane * 8;

    f32x4 acc[4][4];                              // single merged accumulator: 64 AGPR
#pragma unroll
    for (int ii = 0; ii < 4; ++ii)
#pragma unroll
        for (int j = 0; j < 4; ++j)
            acc[ii][j] = (f32x4)0.f;

#pragma unroll
    for (int c = 0; c < NCH; ++c) {
        // 16 independent coalesced loads; no barrier anywhere in the K-loop.
        half8 ah[4], al[4], bh[4], bl[4];
#pragma unroll
        for (int mt = 0; mt < 4; ++mt) {
            ah[mt] = *(const half8*)(gQh + c * CST + mt * 512);
            al[mt] = *(const half8*)(gQl + c * CST + mt * 512);
        }
#pragma unroll
        for (int nt = 0; nt < 4; ++nt) {
            bh[nt] = *(const half8*)(gKh + c * CST + nt * 512);
            bl[nt] = *(const half8*)(gKl + c * CST + nt * 512);
        }

        __builtin_amdgcn_s_setprio(1);
#pragma unroll
        for (int nt = 0; nt < 4; ++nt) {
#pragma unroll
            for (int mt = 0; mt < 4; ++mt) {
                acc[mt][nt] = __builtin_amdgcn_mfma_f32_16x16x32_f16(ah[mt], bh[nt], acc[mt][nt], 0, 0, 0);
                acc[mt][nt] = __builtin_amdgcn_mfma_f32_16x16x32_f16(ah[mt], bl[nt], acc[mt][nt], 0, 0, 0);
                acc[mt][nt] = __builtin_amdgcn_mfma_f32_16x16x32_f16(al[mt], bh[nt], acc[mt][nt], 0, 0, 0);
            }
        }
        __builtin_amdgcn_s_setprio(0);
    }

    // epilogue: dist = kn - 2*acc; packed order-preserving u64; shfl_xor(1) col-pair
    // pre-combine -> [128][17] u64 LDS (u64 lexicographic min == (value asc, idx asc)).
    float knv[4];
    int nglob[4];
#pragma unroll
    for (int nt = 0; nt < 4; ++nt) {
        nglob[nt] = n0 + nbase + nt * 16 + l15;
        knv[nt] = kn[nglob[nt]];
    }
    unsigned long long* redu = (unsigned long long*)smem;   // [128][17] u64
    const int cidx2 = (nbase >> 3) + (l15 >> 1);            // 0..15 after pair-combine

#pragma unroll
    for (int mt = 0; mt < 4; ++mt)
#pragma unroll
        for (int r = 0; r < 4; ++r) {
            float bv = 1e38f;
            int bn = 0x7fffffff;
#pragma unroll
            for (int nt = 0; nt < 4; ++nt) {   // ascending n within lane -> strict < ok
                float d = knv[nt] - 2.0f * acc[mt][nt][r];
                if (d < bv) { bv = d; bn = nglob[nt]; }
            }
            unsigned u = __float_as_uint(bv);
            u = (u & 0x80000000u) ? ~u : (u | 0x80000000u);   // order-preserving map
            unsigned long long pk = ((unsigned long long)u << 32) | (unsigned)bn;
            unsigned long long po = __shfl_xor(pk, 1, 64);    // partner col, same row
            pk = (po < pk) ? po : pk;
            if (!(lane & 1)) {
                int m = mbase + mt * 16 + quad * 4 + r;        // C row = quad*4 + reg
                redu[m * 17 + cidx2] = pk;
            }
        }
    __syncthreads();

    {   // 2 threads/row, 8 u64-min each, pair-combine via shfl
        int row = tid >> 1;
        int base = (tid & 1) * 8;
        unsigned long long best = 0xFFFFFFFFFFFFFFFFull;
        const unsigned long long* rp = redu + row * 17 + base;
#pragma unroll
        for (int t2 = 0; t2 < 8; ++t2) {
            unsigned long long v = rp[t2];
            best = (v < best) ? v : best;
        }
        unsigned long long other = __shfl_xor(best, 1, 64);
        best = (other < best) ? other : best;
        if (!(tid & 1)) atomicMin(&out[q0 + row], best);
    }
}

// ---------------- gather + fold (overlap-add mean) ----------------
// 8 lanes per output pixel: lane-slot s=0..6 handles patch-row i=s (7 j-loads, ILP 7),
// s=7 idle; shfl_down(width=8) tree reduces; s==0 divides by ANALYTIC count and stores.
// 864 blocks x 256 = 13.5 waves/CU.
__global__ void k_fold(const float* __restrict__ value,
                       const unsigned long long* __restrict__ fidx64,
                       float* __restrict__ out) {
    int t = blockIdx.x * 256 + threadIdx.x;   // 3*96*96*8 = 221184
    int pix = t >> 3, s = t & 7;
    if (pix >= 3 * IMG * IMG) return;
    int c = pix / (IMG * IMG);
    int rem = pix % (IMG * IMG);
    int Y = rem / IMG, X = rem % IMG;

    float partial = 0.f;
    int yy = Y - s;
    if (s < 7 && (unsigned)yy < (unsigned)HO) {
        const unsigned* fidx32 = (const unsigned*)fidx64;   // low word = row index
        const float* vbase = value + c * 49 + s * 7;
        int rows[7];
        bool oks[7];
#pragma unroll
        for (int j = 0; j < 7; ++j) {
            int xx = X - j;
            bool ok = (unsigned)xx < (unsigned)HO;
            int p = ok ? (yy * HO + xx) : 0;
            rows[j] = (int)fidx32[2 * p];
            oks[j] = ok;
        }
#pragma unroll
        for (int j = 0; j < 7; ++j) {
            float v = vbase[rows[j] * DD + j];   // always in-bounds (row 0 when masked)
            if (oks[j]) partial += v;
        }
    }
    partial += __shfl_down(partial, 4, 8);
    partial += __shfl_down(partial, 2, 8);
    partial += __shfl_down(partial, 1, 8);
    if (s == 0) {
        int i0 = max(0, Y - (HO - 1)), i1 = min(6, Y);
        int j0 = max(0, X - (HO - 1)), j1 = min(6, X);
        float cnt = (float)((i1 - i0 + 1) * (j1 - j0 + 1));
        out[pix] = partial / cnt;
    }
}

extern "C" void kernel_launch(void* const* d_in, const int* in_sizes, int n_in,
                              void* d_out, int out_size, void* d_ws, size_t ws_size,
                              hipStream_t stream) {
    const float* query = (const float*)d_in[0];
    const float* key   = (const float*)d_in[1];
    const float* value = (const float*)d_in[2];
    float* out = (float*)d_out;

    _Float16* Qh = (_Float16*)d_ws;           // ARRN f16 each
    _Float16* Ql = Qh + ARRN;
    _Float16* Kh = Ql + ARRN;
    _Float16* Kl = Kh + ARRN;
    float* kn = (float*)(Kl + ARRN);          // 8192 f32
    unsigned long long* fidx64 = (unsigned long long*)(kn + 8192);   // 8192 u64

    dim3 gp(768, 2);   // 640 split blocks + 128 fused-kn blocks (y==1)
    k_prep<<<gp, 256, 0, stream>>>(query, key, Qh, Ql, Kh, Kl, kn, fidx64);
    k_nn<<<4096, 256, 0, stream>>>(Qh, Ql, Kh, Kl, kn, fidx64);
    k_fold<<<864, 256, 0, stream>>>(value, fidx64, out);
}